// Round 4
// baseline (7451.102 us; speedup 1.0000x reference)
//
#include <hip/hip_runtime.h>
#include <stdint.h>

#define T_STEPS 320
#define BATCH   192
#define HID     1024
#define NBLK    256

typedef unsigned short u16;
typedef __bf16 bf16x8 __attribute__((ext_vector_type(8)));
typedef float  f32x4  __attribute__((ext_vector_type(4)));
typedef unsigned int u32x4 __attribute__((ext_vector_type(4)));

// ---------------- workspace layout (bytes) ----------------
#define OFF_LOGITS   0u          // [192][320] f32 = 245760
#define OFF_FLAGS    245760u     // [4 grp][64 jsl] u32 at 64B stride = 16384
#define MEMSET_BYTES 262144u
#define OFF_C0       262144u     // [2][192][1024] f32 = 1572864
#define OFF_H        1835008u    // [2 dir][2 buf][192][1024] bf16 = 1572864
#define OFF_WPACK    3407872u    // packed W_hh bf16 fragments = 16777216
#define OFF_COEF     20185088u   // [2][64][64] float4 (w0,w1,bias,0) = 131072
#define WS_NEED      20316160u

__device__ __forceinline__ u16 f2bf(float f) {
  unsigned u = __float_as_uint(f);
  unsigned r = (u + 0x7FFFu + ((u >> 16) & 1u)) >> 16;
  return (u16)r;
}
__device__ __forceinline__ float sigm(float x)   { return 1.f / (1.f + __expf(-x)); }
__device__ __forceinline__ float tanh_f(float x) { return 1.f - 2.f / (1.f + __expf(2.f * x)); }

// ---------------- prep: pack W_hh into MFMA-fragment order (bf16) ----------------
__global__ void pack_k(const float* __restrict__ Whhf, const float* __restrict__ Whhb,
                       u16* __restrict__ wpack)
{
  int lin = blockIdx.x * 256 + threadIdx.x;      // < 1048576
  int lane = lin & 63;
  int cg   = (lin >> 6) & 3;
  int ks   = (lin >> 8) & 31;
  int jsl  = (lin >> 13) & 63;
  int dir  = (lin >> 19) & 1;
  int col  = cg * 16 + (lane & 15);
  int R    = (col & 3) * 1024 + jsl * 16 + (col >> 2);
  int kb   = ks * 32 + (lane >> 4) * 8;
  const float* W = dir ? Whhb : Whhf;
  const float* src = W + (size_t)R * 1024 + kb;
  unsigned w[4];
  #pragma unroll
  for (int e = 0; e < 4; ++e) {
    unsigned lo = f2bf(src[2 * e]);
    unsigned hi = f2bf(src[2 * e + 1]);
    w[e] = lo | (hi << 16);
  }
  *((uint4*)(wpack + (size_t)lin * 8)) = make_uint4(w[0], w[1], w[2], w[3]);
}

// ---------------- prep: per-gate-row x-projection coefficients ----------------
__global__ void coef_k(const float* __restrict__ Wihf, const float* __restrict__ bihf,
                       const float* __restrict__ bhhf,
                       const float* __restrict__ Wihb, const float* __restrict__ bihb,
                       const float* __restrict__ bhhb, float* __restrict__ coef)
{
  int id  = blockIdx.x * 256 + threadIdx.x;      // < 8192
  int col = id & 63;
  int jsl = (id >> 6) & 63;
  int dir = (id >> 12) & 1;
  int R   = (col & 3) * 1024 + jsl * 16 + (col >> 2);
  const float* Wih = dir ? Wihb : Wihf;
  const float* bi  = dir ? bihb : bihf;
  const float* bh  = dir ? bhhb : bhhf;
  float4 v;
  v.x = Wih[(size_t)R * 2 + 0];
  v.y = Wih[(size_t)R * 2 + 1];
  v.z = bi[R] + bh[R];
  v.w = 0.f;
  ((float4*)coef)[id] = v;
}

// ---------------- prep: h0/c0 projections ----------------
__global__ void init_k(const float* __restrict__ ctrl, const float* __restrict__ ratw,
                       const float* __restrict__ Whf, const float* __restrict__ bhf,
                       const float* __restrict__ Whb, const float* __restrict__ bhb,
                       const float* __restrict__ Wcf, const float* __restrict__ bcf,
                       const float* __restrict__ Wcb, const float* __restrict__ bcb,
                       u16* hb, float* c0)
{
  int idx = blockIdx.x * 256 + threadIdx.x;      // 0..196607
  int m = blockIdx.y;                             // 0 h0f, 1 h0b, 2 c0f, 3 c0b
  int b = idx >> 10;
  int h = idx & 1023;
  const float* W  = (m == 0) ? Whf : (m == 1) ? Whb : (m == 2) ? Wcf : Wcb;
  const float* bi = (m == 0) ? bhf : (m == 1) ? bhb : (m == 2) ? bcf : bcb;
  float acc = bi[h];
  const float* wr = W + h * 24;
  #pragma unroll
  for (int k = 0; k < 16; ++k) acc += wr[k] * ctrl[b * 16 + k];
  #pragma unroll
  for (int k = 0; k < 8; ++k)  acc += wr[16 + k] * ratw[b * 8 + k];
  acc = tanh_f(acc);
  if (m < 2) hb[((size_t)(m * 2 + 0) * BATCH + b) * HID + h] = f2bf(acc);
  else       c0[((size_t)(m - 2) * BATCH + b) * HID + h] = acc;
}

// ---------------- persistent bi-LSTM: flag-dataflow sync, no global barrier ----------------
// block: dir = bid>>7, bhalf = (bid>>6)&1, jsl = bid&63. 512 threads.
// wave w = wm*4 + wn*2 + wk: wm rows-48-half, wn cols-32-half, wk K-512-half.
// Sync group = (dir,bhalf): 64 blocks, one monotonic flag per producer block.

#define ENSURE(P) do { \
    if (!((ready >> (P)) & 1ull)) { \
      const unsigned* fp_ = gflags + (unsigned)(P) * 16; \
      int g_ = 0; unsigned fv_; \
      for (;;) { \
        asm volatile("global_load_dword %0, %1, off sc0 sc1" : "=v"(fv_) : "v"(fp_)); \
        asm volatile("s_waitcnt vmcnt(0)" ::: "memory"); \
        if ((int)fv_ >= starget || ++g_ > (1 << 22)) break; \
        __builtin_amdgcn_s_sleep(2); \
      } \
      ready |= (1ull << (P)); \
    } \
  } while (0); \
  __builtin_amdgcn_sched_barrier(0);

#define PRE(I, S) { const int c_ = cs[I]; \
  ENSURE(wkbase + 2 * c_); ENSURE(wkbase + 2 * c_ + 1); \
  const u16* a0_ = ab0 + c_ * 32; const u16* a1_ = ab1 + c_ * 32; const u16* a2_ = ab2 + c_ * 32; \
  asm volatile("global_load_dwordx4 %0, %1, off sc0 sc1" : "=v"(aq[S][0]) : "v"(a0_)); \
  asm volatile("global_load_dwordx4 %0, %1, off sc0 sc1" : "=v"(aq[S][1]) : "v"(a1_)); \
  asm volatile("global_load_dwordx4 %0, %1, off sc0 sc1" : "=v"(aq[S][2]) : "v"(a2_)); }

#define PREB(I, S) { const int c_ = cs[I]; \
  bv[S][0] = *(const bf16x8*)(bW + c_ * 2048); \
  bv[S][1] = *(const bf16x8*)(bW + c_ * 2048 + 512); }

#define WB(n) \
  asm volatile("s_waitcnt vmcnt(" #n ")" ::: "memory"); \
  __builtin_amdgcn_sched_barrier(0);

#define MM(s, p) { \
  _Pragma("unroll") \
  for (int mt_ = 0; mt_ < 3; ++mt_) { \
    bf16x8 a_ = __builtin_bit_cast(bf16x8, aq[s][mt_]); \
    acc[mt_][0] = __builtin_amdgcn_mfma_f32_16x16x32_bf16(a_, bv[p][0], acc[mt_][0], 0, 0, 0); \
    acc[mt_][1] = __builtin_amdgcn_mfma_f32_16x16x32_bf16(a_, bv[p][1], acc[mt_][1], 0, 0, 0); \
  } \
}

#define HST(PT, VL) asm volatile("global_store_short %0, %1, off sc0 sc1" :: "v"(PT), "v"(VL) : "memory")

#define SWZ(Q) ((((Q) & 3) << 4) | (((Q) & 4) << 1))

__launch_bounds__(512, 1)
__global__ void lstm_persist(const float* __restrict__ x,
                             const float* __restrict__ wlog,
                             float* logits,
                             const float* __restrict__ c0,
                             u16* hb,
                             const u16* __restrict__ wpack,
                             const float* __restrict__ coef,
                             unsigned* flags)
{
  extern __shared__ char lds[];
  u16*   Wlds = (u16*)lds;                    // [32 ks][4 cg][64 lane][8] bf16 = 128 KiB
  float* DMP  = (float*)(lds + 131072);       // [8 regions][8 q][64 lane] f32 = 16 KiB (XOR-swizzled)

  const int tid   = threadIdx.x;
  const int bid   = blockIdx.x;
  const int dir   = bid >> 7;
  const int bhalf = (bid >> 6) & 1;
  const int jsl   = bid & 63;
  const int wave  = tid >> 6;
  const int lane  = tid & 63;
  const int wm    = wave >> 2;
  const int wn    = (wave >> 1) & 1;
  const int wk    = wave & 1;
  const int wn2   = wn * 2;
  const int pairR = (wm * 2 + wn) * 2;        // region pair base (wk0, wk1 = +1)
  const int wkbase = wk * 32;
  const int rot   = jsl & 15;                 // de-convoy L3: per-block K-chunk rotation

  unsigned* gflags = flags + (dir * 2 + bhalf) * 64 * 16;   // 64B-stride flags
  unsigned* myflag = gflags + jsl * 16;

  { // W slice -> LDS once (read-only, normal cached path)
    const uint4* wsrc = (const uint4*)wpack + (size_t)(dir * 64 + jsl) * 8192;
    uint4* wdst = (uint4*)Wlds;
    for (int i = tid; i < 8192; i += 512) wdst[i] = wsrc[i];
  }

  const int jj    = lane & 7;
  const int jglob = jsl * 16 + wn * 8 + jj;
  float4 cf0, cf1, cf2, cf3;
  {
    const float4* cp = (const float4*)coef + ((dir * 64 + jsl) * 64 + wn * 32 + jj * 4);
    cf0 = cp[0]; cf1 = cp[1]; cf2 = cp[2]; cf3 = cp[3];
  }
  const float wlg = wlog[dir * 1024 + jglob];

  // pointwise ownership: rows b_loc = 16*mt + 8*wk + (lane>>3)
  const int bsub = lane >> 3;                 // 0..7
  float creg[3];
  int   bgm[3];
  #pragma unroll
  for (int mt = 0; mt < 3; ++mt) {
    int b_loc = 16 * mt + 8 * wk + bsub;
    int bg = bhalf * 96 + wm * 48 + b_loc;
    bgm[mt] = bg;
    creg[mt] = c0[((size_t)dir * BATCH + bg) * HID + jglob];
  }

  const int arow0 = bhalf * 96 + wm * 48 + 0 * 16 + (lane & 15);
  const int arow1 = arow0 + 16;
  const int arow2 = arow0 + 32;
  const int koff  = wk * 512 + (lane >> 4) * 8;   // u16 units (chunk 0 base)

  const u16* bW = Wlds + ((size_t)(wk * 64 + wn2) * 64 + lane) * 8;

  int cs[16];
  #pragma unroll
  for (int i = 0; i < 16; ++i) cs[i] = (rot + i) & 15;

  // stashed logit contributions (issued one step late, off the drain path)
  float lpv[3] = {0.f, 0.f, 0.f};
  int   lpo[3] = {0, 0, 0};

  __syncthreads();

  for (int s = 0; s < T_STEPS; ++s) {
    const int starget = s;
    const int rbuf = s & 1;
    const u16* hsrc = hb + ((size_t)(dir * 2 + rbuf)) * BATCH * HID;
    u16*       hdst = hb + ((size_t)(dir * 2 + (rbuf ^ 1))) * BATCH * HID;
    const u16* ab0 = hsrc + (size_t)arow0 * HID + koff;
    const u16* ab1 = hsrc + (size_t)arow1 * HID + koff;
    const u16* ab2 = hsrc + (size_t)arow2 * HID + koff;

    // ---- flag snapshot (one lane-parallel load + ballot) ----
    unsigned fval;
    {
      const unsigned* fsp = gflags + lane * 16;
      asm volatile("global_load_dword %0, %1, off sc0 sc1" : "=v"(fval) : "v"(fsp));
      asm volatile("s_waitcnt vmcnt(0)" ::: "memory");
    }
    unsigned long long ready = __ballot((int)fval >= starget);
    __builtin_amdgcn_sched_barrier(0);

    // ---- previous step's logit atomics (overlap with this step's GEMM) ----
    if (s > 0 && jj == 0) {
      atomicAdd(&logits[lpo[0]], lpv[0]);
      atomicAdd(&logits[lpo[1]], lpv[1]);
      atomicAdd(&logits[lpo[2]], lpv[2]);
    }

    f32x4 acc[3][2];
    #pragma unroll
    for (int mt = 0; mt < 3; ++mt) {
      acc[mt][0] = (f32x4){0.f, 0.f, 0.f, 0.f};
      acc[mt][1] = (f32x4){0.f, 0.f, 0.f, 0.f};
    }

    u32x4  aq[6][3];
    bf16x8 bv[3][2];

    // 16 K-chunks (32 k each), flag-gated, rotated start, ring-6 A / ring-3 B
    PRE(0, 0) PRE(1, 1) PRE(2, 2) PRE(3, 3) PRE(4, 4)
    PREB(0, 0) PREB(1, 1)

    PRE(5, 5)   PREB(2, 2)   WB(15) MM(0, 0)
    PRE(6, 0)   PREB(3, 0)   WB(15) MM(1, 1)
    PRE(7, 1)   PREB(4, 1)   WB(15) MM(2, 2)
    PRE(8, 2)   PREB(5, 2)   WB(15) MM(3, 0)
    PRE(9, 3)   PREB(6, 0)   WB(15) MM(4, 1)
    PRE(10, 4)  PREB(7, 1)   WB(15) MM(5, 2)
    PRE(11, 5)  PREB(8, 2)   WB(15) MM(0, 0)
    PRE(12, 0)  PREB(9, 0)   WB(15) MM(1, 1)
    PRE(13, 1)  PREB(10, 1)  WB(15) MM(2, 2)
    PRE(14, 2)  PREB(11, 2)  WB(15) MM(3, 0)
    PRE(15, 3)  PREB(12, 0)  WB(15) MM(4, 1)
                PREB(13, 1)  WB(12) MM(5, 2)
                PREB(14, 2)  WB(9)  MM(0, 0)
                PREB(15, 0)  WB(6)  MM(1, 1)
                             WB(3)  MM(2, 2)
                             WB(0)  MM(3, 0)

    const int t_x = dir ? (T_STEPS - 1 - s) : s;

    // 3 row-block phases: swizzled dump -> sync -> gather own+partner K-half -> pointwise
    #pragma unroll
    for (int mt = 0; mt < 3; ++mt) {
      float* myreg = DMP + (pairR + wk) * 512;
      #pragma unroll
      for (int cgi = 0; cgi < 2; ++cgi)
        #pragma unroll
        for (int r = 0; r < 4; ++r) {
          const int q = cgi * 4 + r;
          myreg[q * 64 + (lane ^ SWZ(q))] = acc[mt][cgi][r];
        }
      __syncthreads();

      {
        int bg   = bgm[mt];
        int q4   = (jj >> 2) * 4 + (bsub & 3);
        int ldw  = ((8 * wk + (bsub & 4)) << 2) + (jj & 3) * 4;
        int goff = q4 * 64 + (ldw ^ SWZ(q4));
        const f32x4 pa = *(const f32x4*)(DMP + pairR * 512 + goff);
        const f32x4 pb = *(const f32x4*)(DMP + (pairR + 1) * 512 + goff);
        float gi = pa[0] + pb[0];
        float gf = pa[1] + pb[1];
        float gg = pa[2] + pb[2];
        float go = pa[3] + pb[3];
        float2 xv = *(const float2*)(x + ((size_t)t_x * BATCH + bg) * 2);
        float pi = gi + cf0.x * xv.x + cf0.y * xv.y + cf0.z;
        float pf = gf + cf1.x * xv.x + cf1.y * xv.y + cf1.z;
        float pg = gg + cf2.x * xv.x + cf2.y * xv.y + cf2.z;
        float po = go + cf3.x * xv.x + cf3.y * xv.y + cf3.z;
        float ig = sigm(pi), fg = sigm(pf), gv = tanh_f(pg), og = sigm(po);
        float c = fg * creg[mt] + ig * gv;
        creg[mt] = c;
        float h = og * tanh_f(c);
        u16* hp = hdst + (size_t)bg * HID + jglob;
        unsigned hv = (unsigned)f2bf(h);
        HST(hp, hv);
        float lp = h * wlg;
        lp += __shfl_xor(lp, 1);
        lp += __shfl_xor(lp, 2);
        lp += __shfl_xor(lp, 4);
        lpv[mt] = lp;
        lpo[mt] = bg * T_STEPS + t_x;
      }
      __syncthreads();   // protect DMP before next mt overwrites
    }

    // drain own h stores, block-sync (=> all 64 producer gates passed by all waves), flag bump
    asm volatile("s_waitcnt vmcnt(0)" ::: "memory");
    __syncthreads();
    if (tid == 0) {
      unsigned nv = (unsigned)(s + 1);
      asm volatile("global_store_dword %0, %1, off sc0 sc1" :: "v"(myflag), "v"(nv) : "memory");
    }
  }

  // final step's logit atomics
  if (jj == 0) {
    atomicAdd(&logits[lpo[0]], lpv[0]);
    atomicAdd(&logits[lpo[1]], lpv[1]);
    atomicAdd(&logits[lpo[2]], lpv[2]);
  }
}

// ---------------- post: softmax -> cumsum -> rational Bezier -> curves + reg ----------------
__global__ void post_k(const float* __restrict__ logits, const float* __restrict__ ctrl,
                       const float* __restrict__ ratw, float* __restrict__ out)
{
  __shared__ float sh[T_STEPS + 64];
  const int b = blockIdx.x;
  const int t = threadIdx.x;          // 320 threads
  float l = logits[b * T_STEPS + t];
  sh[t] = l;
  __syncthreads();
  if (t < 64) {
    float mm = sh[t];
    for (int i = t + 64; i < T_STEPS; i += 64) mm = fmaxf(mm, sh[i]);
    #pragma unroll
    for (int o = 32; o; o >>= 1) mm = fmaxf(mm, __shfl_xor(mm, o));
    if (t == 0) sh[T_STEPS] = mm;
  }
  __syncthreads();
  const float m = sh[T_STEPS];
  float e = __expf(l - m);
  __syncthreads();
  sh[t] = e;
  __syncthreads();
  for (int off = 1; off < T_STEPS; off <<= 1) {
    float v = (t >= off) ? sh[t - off] : 0.f;
    __syncthreads();
    sh[t] += v;
    __syncthreads();
  }
  const float total = sh[T_STEPS - 1];
  const float ts = sh[t] / total;

  float px[8], py[8], rr[8];
  #pragma unroll
  for (int n = 0; n < 8; ++n) {
    px[n] = ctrl[b * 16 + 2 * n];
    py[n] = ctrl[b * 16 + 2 * n + 1];
    rr[n] = ratw[b * 8 + n];
  }
  const float C[8] = {1.f, 7.f, 21.f, 35.f, 35.f, 21.f, 7.f, 1.f};
  float tp[8], up[8];
  tp[0] = 1.f; up[0] = 1.f;
  const float u = 1.f - ts;
  #pragma unroll
  for (int n = 1; n < 8; ++n) { tp[n] = tp[n - 1] * ts; up[n] = up[n - 1] * u; }
  float den = 0.f, nx = 0.f, ny = 0.f;
  #pragma unroll
  for (int n = 0; n < 8; ++n) {
    float w = C[n] * tp[n] * up[7 - n] * rr[n];
    den += w; nx += w * px[n]; ny += w * py[n];
  }
  out[(b * T_STEPS + t) * 2 + 0] = nx / den;
  out[(b * T_STEPS + t) * 2 + 1] = ny / den;

  if (b == 0) {   // regularizer scalar
    __syncthreads();
    if (t < BATCH) {
      float s2 = 0.f;
      #pragma unroll
      for (int n = 0; n < 7; ++n) {
        float dx = ctrl[t * 16 + 2 * n + 2] - ctrl[t * 16 + 2 * n + 0];
        float dy = ctrl[t * 16 + 2 * n + 3] - ctrl[t * 16 + 2 * n + 1];
        s2 += dx * dx + dy * dy;
      }
      sh[t] = s2;
    }
    __syncthreads();
    if (t == 0) {
      float tot = 0.f;
      for (int i = 0; i < BATCH; ++i) tot += sh[i];
      out[BATCH * T_STEPS * 2] = tot / (float)(BATCH * 7);
    }
  }
}

extern "C" void kernel_launch(void* const* d_in, const int* in_sizes, int n_in,
                              void* d_out, int out_size, void* d_ws, size_t ws_size,
                              hipStream_t stream)
{
  const float* x    = (const float*)d_in[0];
  const float* ctrl = (const float*)d_in[1];
  const float* ratw = (const float*)d_in[2];
  const float* Whf  = (const float*)d_in[3];
  const float* bhf  = (const float*)d_in[4];
  const float* Whb  = (const float*)d_in[5];
  const float* bhb  = (const float*)d_in[6];
  const float* Wcf  = (const float*)d_in[7];
  const float* bcf  = (const float*)d_in[8];
  const float* Wcb  = (const float*)d_in[9];
  const float* bcb  = (const float*)d_in[10];
  const float* Wihf = (const float*)d_in[11];
  const float* Whhf = (const float*)d_in[12];
  const float* bihf = (const float*)d_in[13];
  const float* bhhf = (const float*)d_in[14];
  const float* Wihb = (const float*)d_in[15];
  const float* Whhb = (const float*)d_in[16];
  const float* bihb = (const float*)d_in[17];
  const float* bhhb = (const float*)d_in[18];
  const float* Wlog = (const float*)d_in[19];
  float* out = (float*)d_out;
  char*  ws  = (char*)d_ws;
  if (ws_size < (size_t)WS_NEED) return;

  float*    logits = (float*)(ws + OFF_LOGITS);
  unsigned* flags  = (unsigned*)(ws + OFF_FLAGS);
  float*    c0     = (float*)(ws + OFF_C0);
  u16*      hb     = (u16*)(ws + OFF_H);
  u16*      wpack  = (u16*)(ws + OFF_WPACK);
  float*    coef   = (float*)(ws + OFF_COEF);

  hipMemsetAsync(ws, 0, MEMSET_BYTES, stream);
  pack_k<<<4096, 256, 0, stream>>>(Whhf, Whhb, wpack);
  coef_k<<<32, 256, 0, stream>>>(Wihf, bihf, bhhf, Wihb, bihb, bhhb, coef);
  init_k<<<dim3(768, 4), 256, 0, stream>>>(ctrl, ratw, Whf, bhf, Whb, bhb,
                                           Wcf, bcf, Wcb, bcb, hb, c0);
  hipFuncSetAttribute((const void*)lstm_persist,
                      hipFuncAttributeMaxDynamicSharedMemorySize, 147456);
  lstm_persist<<<NBLK, 512, 147456, stream>>>(x, Wlog, logits, c0, hb, wpack, coef, flags);
  post_k<<<BATCH, T_STEPS, 0, stream>>>(logits, ctrl, ratw, out);
}

// Round 5
// 4932.204 us; speedup vs baseline: 1.5107x; 1.5107x over previous
//
#include <hip/hip_runtime.h>
#include <stdint.h>

#define T_STEPS 320
#define BATCH   192
#define HID     1024
#define NBLK    256
#define NBLK_DIR 128

typedef unsigned short u16;
typedef __bf16 bf16x8 __attribute__((ext_vector_type(8)));
typedef float  f32x4  __attribute__((ext_vector_type(4)));
typedef unsigned int u32x4 __attribute__((ext_vector_type(4)));

// ---------------- workspace layout (bytes) ----------------
#define OFF_LOGITS   0u          // [192][320] f32 = 245760
#define OFF_BAR      245760u     // 2 x u32 monotonic barrier counters, 128B apart
#define MEMSET_BYTES 246016u
#define OFF_C0       262144u     // [2][192][1024] f32 = 1572864
#define OFF_H        1835008u    // [2 dir][2 buf][192][1024] bf16 = 1572864
#define OFF_WPACK    3407872u    // packed W_hh bf16 fragments = 16777216
#define OFF_COEF     20185088u   // [2][64][64] float4 (w0,w1,bias,0) = 131072
#define WS_NEED      20316160u

// LDS: reduction buffer, 24 regions x (64 lanes x 17 pad-slots) floats
#define DMP_REG_STRIDE 1088      // floats per region (64*17)
#define DMP_BYTES      104448    // 24 * 1088 * 4
#define DYN_LDS        104464

__device__ __forceinline__ u16 f2bf(float f) {
  unsigned u = __float_as_uint(f);
  unsigned r = (u + 0x7FFFu + ((u >> 16) & 1u)) >> 16;
  return (u16)r;
}
__device__ __forceinline__ float sigm(float x)   { return 1.f / (1.f + __expf(-x)); }
__device__ __forceinline__ float tanh_f(float x) { return 1.f - 2.f / (1.f + __expf(2.f * x)); }

// ---------------- prep: pack W_hh into MFMA-fragment order (bf16) ----------------
// [dir][jsl][ks 0..31][cg 0..3][lane 0..63][8 elems]; col = cg*16+(lane&15)
__global__ void pack_k(const float* __restrict__ Whhf, const float* __restrict__ Whhb,
                       u16* __restrict__ wpack)
{
  int lin = blockIdx.x * 256 + threadIdx.x;      // < 1048576
  int lane = lin & 63;
  int cg   = (lin >> 6) & 3;
  int ks   = (lin >> 8) & 31;
  int jsl  = (lin >> 13) & 63;
  int dir  = (lin >> 19) & 1;
  int col  = cg * 16 + (lane & 15);
  int R    = (col & 3) * 1024 + jsl * 16 + (col >> 2);
  int kb   = ks * 32 + (lane >> 4) * 8;
  const float* W = dir ? Whhb : Whhf;
  const float* src = W + (size_t)R * 1024 + kb;
  unsigned w[4];
  #pragma unroll
  for (int e = 0; e < 4; ++e) {
    unsigned lo = f2bf(src[2 * e]);
    unsigned hi = f2bf(src[2 * e + 1]);
    w[e] = lo | (hi << 16);
  }
  *((uint4*)(wpack + (size_t)lin * 8)) = make_uint4(w[0], w[1], w[2], w[3]);
}

// ---------------- prep: per-gate-row x-projection coefficients ----------------
__global__ void coef_k(const float* __restrict__ Wihf, const float* __restrict__ bihf,
                       const float* __restrict__ bhhf,
                       const float* __restrict__ Wihb, const float* __restrict__ bihb,
                       const float* __restrict__ bhhb, float* __restrict__ coef)
{
  int id  = blockIdx.x * 256 + threadIdx.x;      // < 8192
  int col = id & 63;
  int jsl = (id >> 6) & 63;
  int dir = (id >> 12) & 1;
  int R   = (col & 3) * 1024 + jsl * 16 + (col >> 2);
  const float* Wih = dir ? Wihb : Wihf;
  const float* bi  = dir ? bihb : bihf;
  const float* bh  = dir ? bhhb : bhhf;
  float4 v;
  v.x = Wih[(size_t)R * 2 + 0];
  v.y = Wih[(size_t)R * 2 + 1];
  v.z = bi[R] + bh[R];
  v.w = 0.f;
  ((float4*)coef)[id] = v;
}

// ---------------- prep: h0/c0 projections ----------------
__global__ void init_k(const float* __restrict__ ctrl, const float* __restrict__ ratw,
                       const float* __restrict__ Whf, const float* __restrict__ bhf,
                       const float* __restrict__ Whb, const float* __restrict__ bhb,
                       const float* __restrict__ Wcf, const float* __restrict__ bcf,
                       const float* __restrict__ Wcb, const float* __restrict__ bcb,
                       u16* hb, float* c0)
{
  int idx = blockIdx.x * 256 + threadIdx.x;      // 0..196607
  int m = blockIdx.y;                             // 0 h0f, 1 h0b, 2 c0f, 3 c0b
  int b = idx >> 10;
  int h = idx & 1023;
  const float* W  = (m == 0) ? Whf : (m == 1) ? Whb : (m == 2) ? Wcf : Wcb;
  const float* bi = (m == 0) ? bhf : (m == 1) ? bhb : (m == 2) ? bcf : bcb;
  float acc = bi[h];
  const float* wr = W + h * 24;
  #pragma unroll
  for (int k = 0; k < 16; ++k) acc += wr[k] * ctrl[b * 16 + k];
  #pragma unroll
  for (int k = 0; k < 8; ++k)  acc += wr[16 + k] * ratw[b * 8 + k];
  acc = tanh_f(acc);
  if (m < 2) hb[((size_t)(m * 2 + 0) * BATCH + b) * HID + h] = f2bf(acc);
  else       c0[((size_t)(m - 2) * BATCH + b) * HID + h] = acc;
}

// ---------------- persistent bi-LSTM ----------------
// 256 blocks x 512 threads. block: dir=bid>>7, bhalf=(bid>>6)&1, jsl=bid&63.
// wave = wm*4+wk: wm in {0,1} rows-48, wk in {0..3} K-quarter-256; each wave all 64 cols.
// A (h) from L3 via sc0sc1 (loaded ONCE per block - no wn duplication).
// B (W) via normal cached loads: slice L2-resident (2 MB/XCD, shared by bhalf pair).
// wk partial sums combined through a single-phase LDS buffer (pad-17, conflict-free).

#define ALD(S, OB) \
  asm volatile("global_load_dwordx4 %0, %1, off offset:" #OB " sc0 sc1" : "=v"(aq[S][0]) : "v"(ab0)); \
  asm volatile("global_load_dwordx4 %0, %1, off offset:" #OB " sc0 sc1" : "=v"(aq[S][1]) : "v"(ab1)); \
  asm volatile("global_load_dwordx4 %0, %1, off offset:" #OB " sc0 sc1" : "=v"(aq[S][2]) : "v"(ab2));

#define BLD(S, C) { const u16* bp_ = wb + (C) * 2048; \
  asm volatile("global_load_dwordx4 %0, %1, off offset:0"    : "=v"(bq[S][0]) : "v"(bp_)); \
  asm volatile("global_load_dwordx4 %0, %1, off offset:1024" : "=v"(bq[S][1]) : "v"(bp_)); \
  asm volatile("global_load_dwordx4 %0, %1, off offset:2048" : "=v"(bq[S][2]) : "v"(bp_)); \
  asm volatile("global_load_dwordx4 %0, %1, off offset:3072" : "=v"(bq[S][3]) : "v"(bp_)); }

#define SB __builtin_amdgcn_sched_barrier(0);

#define WB(n) \
  asm volatile("s_waitcnt vmcnt(" #n ")" ::: "memory"); \
  __builtin_amdgcn_sched_barrier(0);

#define MM(I) { \
  _Pragma("unroll") \
  for (int mt_ = 0; mt_ < 3; ++mt_) { \
    bf16x8 a_ = __builtin_bit_cast(bf16x8, aq[(I) & 3][mt_]); \
    _Pragma("unroll") \
    for (int n_ = 0; n_ < 4; ++n_) { \
      bf16x8 b_ = __builtin_bit_cast(bf16x8, bq[(I) & 3][n_]); \
      acc[mt_][n_] = __builtin_amdgcn_mfma_f32_16x16x32_bf16(a_, b_, acc[mt_][n_], 0, 0, 0); \
    } \
  } }

#define HST(PT, VL) asm volatile("global_store_short %0, %1, off sc0 sc1" :: "v"(PT), "v"(VL) : "memory")

__launch_bounds__(512, 1)
__global__ void lstm_persist(const float* __restrict__ x,
                             const float* __restrict__ wlog,
                             float* logits,
                             const float* __restrict__ c0,
                             u16* hb,
                             const u16* __restrict__ wpack,
                             const float* __restrict__ coef,
                             unsigned* bar)
{
  extern __shared__ char lds[];
  float* DMP = (float*)lds;                     // 24 regions x 1088 floats = 102 KiB
  int* ldsflag = (int*)(lds + DMP_BYTES);

  const int tid   = threadIdx.x;
  const int bid   = blockIdx.x;
  const int dir   = bid >> 7;
  const int bhalf = (bid >> 6) & 1;
  const int jsl   = bid & 63;
  const int wave  = tid >> 6;
  const int lane  = tid & 63;
  const int wm    = wave >> 2;                  // row half (48 rows)
  const int wk    = wave & 3;                   // K quarter (256)

  if (tid == 0) *ldsflag = 0;

  // ---- pointwise ownership: thread -> (rows r = 3*(tid>>4)+mt, hidden jj = tid&15) ----
  const int rgrp = tid >> 4;                    // 0..31
  const int jj   = tid & 15;
  const int jglob = jsl * 16 + jj;
  float4 cf0, cf1, cf2, cf3;
  {
    const float4* cp = (const float4*)coef + ((dir * 64 + jsl) * 64 + jj * 4);
    cf0 = cp[0]; cf1 = cp[1]; cf2 = cp[2]; cf3 = cp[3];
  }
  const float wlg = wlog[dir * 1024 + jglob];

  float creg[3];
  int   bgm[3];
  #pragma unroll
  for (int mt = 0; mt < 3; ++mt) {
    int r  = rgrp * 3 + mt;                     // 0..95
    int bg = bhalf * 96 + r;
    bgm[mt]  = bg;
    creg[mt] = c0[((size_t)dir * BATCH + bg) * HID + jglob];
  }

  // ---- GEMM-side addressing ----
  const int arow0 = bhalf * 96 + wm * 48 + 0 * 16 + (lane & 15);
  const int arow1 = arow0 + 16;
  const int arow2 = arow0 + 32;
  const int koff  = wk * 256 + (lane >> 4) * 8;                    // u16 units
  const u16* wb   = wpack + (size_t)(dir * 64 + jsl) * 65536
                          + (size_t)wk * 8 * 2048 + lane * 8;      // cached (L2) W stream

  // gather constants for the wk-sum
  const int n_g   = jj >> 2;                    // B col-fragment
  const int llo_g = (jj & 3) * 4;               // lane_lo base (gate 0)

  unsigned* cnt = bar + dir * 32;               // 128 B apart

  __syncthreads();

  for (int s = 0; s < T_STEPS; ++s) {
    const int rbuf = s & 1;
    const u16* hsrc = hb + ((size_t)(dir * 2 + rbuf)) * BATCH * HID;
    u16*       hdst = hb + ((size_t)(dir * 2 + (rbuf ^ 1))) * BATCH * HID;
    const u16* ab0 = hsrc + (size_t)arow0 * HID + koff;
    const u16* ab1 = hsrc + (size_t)arow1 * HID + koff;
    const u16* ab2 = hsrc + (size_t)arow2 * HID + koff;

    f32x4 acc[3][4];
    #pragma unroll
    for (int mt = 0; mt < 3; ++mt)
      #pragma unroll
      for (int n = 0; n < 4; ++n)
        acc[mt][n] = (f32x4){0.f, 0.f, 0.f, 0.f};

    u32x4 aq[4][3];
    u32x4 bq[4][4];

    // 8 K-chunks of 32; depth-3 ring-4 prefetch for A (L3) and B (L2), counted vmcnt
    ALD(0, 0)   BLD(0, 0) SB
    ALD(1, 64)  BLD(1, 1) SB
    ALD(2, 128) BLD(2, 2) SB

    ALD(3, 192) BLD(3, 3) WB(21) MM(0)
    ALD(0, 256) BLD(0, 4) WB(21) MM(1)
    ALD(1, 320) BLD(1, 5) WB(21) MM(2)
    ALD(2, 384) BLD(2, 6) WB(21) MM(3)
    ALD(3, 448) BLD(3, 7) WB(21) MM(4)
                          WB(14) MM(5)
                          WB(7)  MM(6)
                          WB(0)  MM(7)

    // ---- dump raw partials: region (wm,mt,n), addr lane*17 + (reg*4+wk) ----
    #pragma unroll
    for (int mt = 0; mt < 3; ++mt)
      #pragma unroll
      for (int n = 0; n < 4; ++n) {
        float* bp = DMP + ((wm * 3 + mt) * 4 + n) * DMP_REG_STRIDE + lane * 17;
        #pragma unroll
        for (int r = 0; r < 4; ++r)
          bp[r * 4 + wk] = acc[mt][n][r];
      }
    __syncthreads();

    const int t_x = dir ? (T_STEPS - 1 - s) : s;

    // ---- gather wk-sum + pointwise for this thread's 3 (row, jj) groups ----
    #pragma unroll
    for (int mt = 0; mt < 3; ++mt) {
      int r    = rgrp * 3 + mt;
      int bg   = bgm[mt];
      int wmr  = (r >= 48) ? 1 : 0;
      int rr   = r - wmr * 48;
      int mt3  = rr >> 4;
      int ri   = rr & 15;
      int Lhi  = ri >> 2;
      int reg  = ri & 3;
      const float* rgn = DMP + ((wmr * 3 + mt3) * 4 + n_g) * DMP_REG_STRIDE + reg * 4;
      float g4[4];
      #pragma unroll
      for (int g = 0; g < 4; ++g) {
        const float* p = rgn + (Lhi * 16 + llo_g + g) * 17;
        g4[g] = (p[0] + p[1]) + (p[2] + p[3]);
      }
      float2 xv = *(const float2*)(x + ((size_t)t_x * BATCH + bg) * 2);
      float pi = g4[0] + cf0.x * xv.x + cf0.y * xv.y + cf0.z;
      float pf = g4[1] + cf1.x * xv.x + cf1.y * xv.y + cf1.z;
      float pg = g4[2] + cf2.x * xv.x + cf2.y * xv.y + cf2.z;
      float po = g4[3] + cf3.x * xv.x + cf3.y * xv.y + cf3.z;
      float ig = sigm(pi), fg = sigm(pf), gv = tanh_f(pg), og = sigm(po);
      float c = fg * creg[mt] + ig * gv;
      creg[mt] = c;
      float h = og * tanh_f(c);
      u16* hp = hdst + (size_t)bg * HID + jglob;
      unsigned hv = (unsigned)f2bf(h);
      HST(hp, hv);
      float lp = h * wlg;
      lp += __shfl_xor(lp, 1);
      lp += __shfl_xor(lp, 2);
      lp += __shfl_xor(lp, 4);
      lp += __shfl_xor(lp, 8);
      if (jj == 0) atomicAdd(&logits[bg * T_STEPS + t_x], lp);
    }

    // drain h stores + atomics to coherence point, then per-direction barrier
    asm volatile("s_waitcnt vmcnt(0)" ::: "memory");
    __syncthreads();
    if (tid == 0) {
      const unsigned target = (unsigned)(s + 1) * NBLK_DIR;
      unsigned old = __hip_atomic_fetch_add(cnt, 1u, __ATOMIC_RELAXED, __HIP_MEMORY_SCOPE_AGENT);
      if (old != target - 1u) {
        long guard = 0;
        while (__hip_atomic_load(cnt, __ATOMIC_RELAXED, __HIP_MEMORY_SCOPE_AGENT) < target) {
          if (++guard > 2000000L) { *ldsflag = 1; break; }
        }
      }
    }
    __syncthreads();
    if (*ldsflag) return;   // co-residency failure: fail cleanly instead of hanging
  }
}

// ---------------- post: softmax -> cumsum -> rational Bezier -> curves + reg ----------------
__global__ void post_k(const float* __restrict__ logits, const float* __restrict__ ctrl,
                       const float* __restrict__ ratw, float* __restrict__ out)
{
  __shared__ float sh[T_STEPS + 64];
  const int b = blockIdx.x;
  const int t = threadIdx.x;          // 320 threads
  float l = logits[b * T_STEPS + t];
  sh[t] = l;
  __syncthreads();
  if (t < 64) {
    float mm = sh[t];
    for (int i = t + 64; i < T_STEPS; i += 64) mm = fmaxf(mm, sh[i]);
    #pragma unroll
    for (int o = 32; o; o >>= 1) mm = fmaxf(mm, __shfl_xor(mm, o));
    if (t == 0) sh[T_STEPS] = mm;
  }
  __syncthreads();
  const float m = sh[T_STEPS];
  float e = __expf(l - m);
  __syncthreads();
  sh[t] = e;
  __syncthreads();
  for (int off = 1; off < T_STEPS; off <<= 1) {
    float v = (t >= off) ? sh[t - off] : 0.f;
    __syncthreads();
    sh[t] += v;
    __syncthreads();
  }
  const float total = sh[T_STEPS - 1];
  const float ts = sh[t] / total;

  float px[8], py[8], rr[8];
  #pragma unroll
  for (int n = 0; n < 8; ++n) {
    px[n] = ctrl[b * 16 + 2 * n];
    py[n] = ctrl[b * 16 + 2 * n + 1];
    rr[n] = ratw[b * 8 + n];
  }
  const float C[8] = {1.f, 7.f, 21.f, 35.f, 35.f, 21.f, 7.f, 1.f};
  float tp[8], up[8];
  tp[0] = 1.f; up[0] = 1.f;
  const float u = 1.f - ts;
  #pragma unroll
  for (int n = 1; n < 8; ++n) { tp[n] = tp[n - 1] * ts; up[n] = up[n - 1] * u; }
  float den = 0.f, nx = 0.f, ny = 0.f;
  #pragma unroll
  for (int n = 0; n < 8; ++n) {
    float w = C[n] * tp[n] * up[7 - n] * rr[n];
    den += w; nx += w * px[n]; ny += w * py[n];
  }
  out[(b * T_STEPS + t) * 2 + 0] = nx / den;
  out[(b * T_STEPS + t) * 2 + 1] = ny / den;

  if (b == 0) {   // regularizer scalar
    __syncthreads();
    if (t < BATCH) {
      float s2 = 0.f;
      #pragma unroll
      for (int n = 0; n < 7; ++n) {
        float dx = ctrl[t * 16 + 2 * n + 2] - ctrl[t * 16 + 2 * n + 0];
        float dy = ctrl[t * 16 + 2 * n + 3] - ctrl[t * 16 + 2 * n + 1];
        s2 += dx * dx + dy * dy;
      }
      sh[t] = s2;
    }
    __syncthreads();
    if (t == 0) {
      float tot = 0.f;
      for (int i = 0; i < BATCH; ++i) tot += sh[i];
      out[BATCH * T_STEPS * 2] = tot / (float)(BATCH * 7);
    }
  }
}

extern "C" void kernel_launch(void* const* d_in, const int* in_sizes, int n_in,
                              void* d_out, int out_size, void* d_ws, size_t ws_size,
                              hipStream_t stream)
{
  const float* x    = (const float*)d_in[0];
  const float* ctrl = (const float*)d_in[1];
  const float* ratw = (const float*)d_in[2];
  const float* Whf  = (const float*)d_in[3];
  const float* bhf  = (const float*)d_in[4];
  const float* Whb  = (const float*)d_in[5];
  const float* bhb  = (const float*)d_in[6];
  const float* Wcf  = (const float*)d_in[7];
  const float* bcf  = (const float*)d_in[8];
  const float* Wcb  = (const float*)d_in[9];
  const float* bcb  = (const float*)d_in[10];
  const float* Wihf = (const float*)d_in[11];
  const float* Whhf = (const float*)d_in[12];
  const float* bihf = (const float*)d_in[13];
  const float* bhhf = (const float*)d_in[14];
  const float* Wihb = (const float*)d_in[15];
  const float* Whhb = (const float*)d_in[16];
  const float* bihb = (const float*)d_in[17];
  const float* bhhb = (const float*)d_in[18];
  const float* Wlog = (const float*)d_in[19];
  float* out = (float*)d_out;
  char*  ws  = (char*)d_ws;
  if (ws_size < (size_t)WS_NEED) return;

  float*    logits = (float*)(ws + OFF_LOGITS);
  unsigned* bar    = (unsigned*)(ws + OFF_BAR);
  float*    c0     = (float*)(ws + OFF_C0);
  u16*      hb     = (u16*)(ws + OFF_H);
  u16*      wpack  = (u16*)(ws + OFF_WPACK);
  float*    coef   = (float*)(ws + OFF_COEF);

  hipMemsetAsync(ws, 0, MEMSET_BYTES, stream);
  pack_k<<<4096, 256, 0, stream>>>(Whhf, Whhb, wpack);
  coef_k<<<32, 256, 0, stream>>>(Wihf, bihf, bhhf, Wihb, bihb, bhhb, coef);
  init_k<<<dim3(768, 4), 256, 0, stream>>>(ctrl, ratw, Whf, bhf, Whb, bhb,
                                           Wcf, bcf, Wcb, bcb, hb, c0);
  hipFuncSetAttribute((const void*)lstm_persist,
                      hipFuncAttributeMaxDynamicSharedMemorySize, DYN_LDS);
  lstm_persist<<<NBLK, 512, DYN_LDS, stream>>>(x, Wlog, logits, c0, hb, wpack, coef, bar);
  post_k<<<BATCH, T_STEPS, 0, stream>>>(logits, ctrl, ratw, out);
}

// Round 6
// 4174.199 us; speedup vs baseline: 1.7850x; 1.1816x over previous
//
#include <hip/hip_runtime.h>
#include <stdint.h>

#define T_STEPS 320
#define BATCH   192
#define HID     1024
#define NBLK    256

typedef unsigned short u16;
typedef __bf16 bf16x8 __attribute__((ext_vector_type(8)));
typedef float  f32x4  __attribute__((ext_vector_type(4)));
typedef unsigned int u32x4 __attribute__((ext_vector_type(4)));

// ---------------- workspace layout (bytes) ----------------
#define OFF_BAR      0u          // [4 grp] x 1KB: lvl1[8]@64B, lvl2@512, release@576
#define OFF_PART     4096u       // [2 dir][8][192][320] f32 partial logits = 3932160
#define MEMSET_BYTES 3936256u
#define OFF_C0       3936256u    // [2][192][1024] f32 = 1572864
#define OFF_H        5509120u    // [2 dir][2 buf][192][1024] bf16 = 1572864
#define OFF_WPACK    7081984u    // packed W_hh bf16 fragments = 16777216
#define OFF_COEF     23859200u   // [2][64][64] float4 = 131072
#define WS_NEED      23990272u

// LDS: DMP [4 wk][96 row][68 (64 col + pad 4)] f32 = 104448 B
#define DMP_WK_STRIDE 6528       // floats (96*68)
#define DMP_BYTES     104448
#define DYN_LDS       104464

__device__ __forceinline__ u16 f2bf(float f) {
  unsigned u = __float_as_uint(f);
  unsigned r = (u + 0x7FFFu + ((u >> 16) & 1u)) >> 16;
  return (u16)r;
}
__device__ __forceinline__ float sigm(float x)   { return 1.f / (1.f + __expf(-x)); }
__device__ __forceinline__ float tanh_f(float x) { return 1.f - 2.f / (1.f + __expf(2.f * x)); }

// ---------------- prep: pack W_hh into MFMA-fragment order (bf16) ----------------
__global__ void pack_k(const float* __restrict__ Whhf, const float* __restrict__ Whhb,
                       u16* __restrict__ wpack)
{
  int lin = blockIdx.x * 256 + threadIdx.x;      // < 1048576
  int lane = lin & 63;
  int cg   = (lin >> 6) & 3;
  int ks   = (lin >> 8) & 31;
  int jsl  = (lin >> 13) & 63;
  int dir  = (lin >> 19) & 1;
  int col  = cg * 16 + (lane & 15);
  int R    = (col & 3) * 1024 + jsl * 16 + (col >> 2);
  int kb   = ks * 32 + (lane >> 4) * 8;
  const float* W = dir ? Whhb : Whhf;
  const float* src = W + (size_t)R * 1024 + kb;
  unsigned w[4];
  #pragma unroll
  for (int e = 0; e < 4; ++e) {
    unsigned lo = f2bf(src[2 * e]);
    unsigned hi = f2bf(src[2 * e + 1]);
    w[e] = lo | (hi << 16);
  }
  *((uint4*)(wpack + (size_t)lin * 8)) = make_uint4(w[0], w[1], w[2], w[3]);
}

// ---------------- prep: per-gate-row x-projection coefficients ----------------
__global__ void coef_k(const float* __restrict__ Wihf, const float* __restrict__ bihf,
                       const float* __restrict__ bhhf,
                       const float* __restrict__ Wihb, const float* __restrict__ bihb,
                       const float* __restrict__ bhhb, float* __restrict__ coef)
{
  int id  = blockIdx.x * 256 + threadIdx.x;      // < 8192
  int col = id & 63;
  int jsl = (id >> 6) & 63;
  int dir = (id >> 12) & 1;
  int R   = (col & 3) * 1024 + jsl * 16 + (col >> 2);
  const float* Wih = dir ? Wihb : Wihf;
  const float* bi  = dir ? bihb : bihf;
  const float* bh  = dir ? bhhb : bhhf;
  float4 v;
  v.x = Wih[(size_t)R * 2 + 0];
  v.y = Wih[(size_t)R * 2 + 1];
  v.z = bi[R] + bh[R];
  v.w = 0.f;
  ((float4*)coef)[id] = v;
}

// ---------------- prep: h0/c0 projections ----------------
__global__ void init_k(const float* __restrict__ ctrl, const float* __restrict__ ratw,
                       const float* __restrict__ Whf, const float* __restrict__ bhf,
                       const float* __restrict__ Whb, const float* __restrict__ bhb,
                       const float* __restrict__ Wcf, const float* __restrict__ bcf,
                       const float* __restrict__ Wcb, const float* __restrict__ bcb,
                       u16* hb, float* c0)
{
  int idx = blockIdx.x * 256 + threadIdx.x;      // 0..196607
  int m = blockIdx.y;                             // 0 h0f, 1 h0b, 2 c0f, 3 c0b
  int b = idx >> 10;
  int h = idx & 1023;
  const float* W  = (m == 0) ? Whf : (m == 1) ? Whb : (m == 2) ? Wcf : Wcb;
  const float* bi = (m == 0) ? bhf : (m == 1) ? bhb : (m == 2) ? bcf : bcb;
  float acc = bi[h];
  const float* wr = W + h * 24;
  #pragma unroll
  for (int k = 0; k < 16; ++k) acc += wr[k] * ctrl[b * 16 + k];
  #pragma unroll
  for (int k = 0; k < 8; ++k)  acc += wr[16 + k] * ratw[b * 8 + k];
  acc = tanh_f(acc);
  if (m < 2) hb[((size_t)(m * 2 + 0) * BATCH + b) * HID + h] = f2bf(acc);
  else       c0[((size_t)(m - 2) * BATCH + b) * HID + h] = acc;
}

// ---------------- persistent bi-LSTM ----------------
// 256 blocks x 512 threads. block: dir=bid>>7, bhalf=(bid>>6)&1, jsl=bid&63.
// wave = wm*4+wk: wm rows-48-half, wk K-quarter-256; each wave covers all 64 cols.
// A (h) via sc0sc1 from coherence point (loaded once per block).
// B (W) via normal cached loads (L2-resident slice).
// Sync: per-(dir,bhalf) 64-block two-level tree barrier, monotonic counters.
// Logits: per-(dir,jsl&7) partial buffers (8-contender atomics, off drain path).

#define ALD(S, OB) \
  asm volatile("global_load_dwordx4 %0, %1, off offset:" #OB " sc0 sc1" : "=v"(aq[S][0]) : "v"(ab0)); \
  asm volatile("global_load_dwordx4 %0, %1, off offset:" #OB " sc0 sc1" : "=v"(aq[S][1]) : "v"(ab1)); \
  asm volatile("global_load_dwordx4 %0, %1, off offset:" #OB " sc0 sc1" : "=v"(aq[S][2]) : "v"(ab2));

#define BLD(S, C) { const u16* bp_ = wb + (C) * 2048; \
  asm volatile("global_load_dwordx4 %0, %1, off offset:0"    : "=v"(bq[S][0]) : "v"(bp_)); \
  asm volatile("global_load_dwordx4 %0, %1, off offset:1024" : "=v"(bq[S][1]) : "v"(bp_)); \
  asm volatile("global_load_dwordx4 %0, %1, off offset:2048" : "=v"(bq[S][2]) : "v"(bp_)); \
  asm volatile("global_load_dwordx4 %0, %1, off offset:3072" : "=v"(bq[S][3]) : "v"(bp_)); }

#define SB __builtin_amdgcn_sched_barrier(0);

#define WB(n) \
  asm volatile("s_waitcnt vmcnt(" #n ")" ::: "memory"); \
  __builtin_amdgcn_sched_barrier(0);

#define MM(I) { \
  _Pragma("unroll") \
  for (int mt_ = 0; mt_ < 3; ++mt_) { \
    bf16x8 a_ = __builtin_bit_cast(bf16x8, aq[(I) & 3][mt_]); \
    _Pragma("unroll") \
    for (int n_ = 0; n_ < 4; ++n_) { \
      bf16x8 b_ = __builtin_bit_cast(bf16x8, bq[(I) & 3][n_]); \
      acc[mt_][n_] = __builtin_amdgcn_mfma_f32_16x16x32_bf16(a_, b_, acc[mt_][n_], 0, 0, 0); \
    } \
  } }

#define HST(PT, VL) asm volatile("global_store_short %0, %1, off sc0 sc1" :: "v"(PT), "v"(VL) : "memory")

__launch_bounds__(512, 1)
__global__ void lstm_persist(const float* __restrict__ x,
                             const float* __restrict__ wlog,
                             float* part,
                             const float* __restrict__ c0,
                             u16* hb,
                             const u16* __restrict__ wpack,
                             const float* __restrict__ coef,
                             unsigned* bar)
{
  extern __shared__ char lds[];
  float* DMP = (float*)lds;                     // [4][96][68] f32
  int* ldsflag = (int*)(lds + DMP_BYTES);

  const int tid   = threadIdx.x;
  const int bid   = blockIdx.x;
  const int dir   = bid >> 7;
  const int bhalf = (bid >> 6) & 1;
  const int jsl   = bid & 63;
  const int wave  = tid >> 6;
  const int lane  = tid & 63;
  const int wm    = wave >> 2;                  // row half (48 rows)
  const int wk    = wave & 3;                   // K quarter (256)
  const int grp   = dir * 2 + bhalf;            // sync group (64 blocks)

  if (tid == 0) *ldsflag = 0;

  // ---- pointwise ownership: thread -> (rows r = 3*(tid>>4)+mt, hidden jj = tid&15) ----
  const int rgrp = tid >> 4;                    // 0..31
  const int jj   = tid & 15;
  const int jglob = jsl * 16 + jj;
  float4 cf0, cf1, cf2, cf3;
  {
    const float4* cp = (const float4*)coef + ((dir * 64 + jsl) * 64 + jj * 4);
    cf0 = cp[0]; cf1 = cp[1]; cf2 = cp[2]; cf3 = cp[3];
  }
  const float wlg = wlog[dir * 1024 + jglob];

  float creg[3];
  int   bgm[3];
  #pragma unroll
  for (int mt = 0; mt < 3; ++mt) {
    int r  = rgrp * 3 + mt;                     // 0..95
    int bg = bhalf * 96 + r;
    bgm[mt]  = bg;
    creg[mt] = c0[((size_t)dir * BATCH + bg) * HID + jglob];
  }

  // ---- GEMM-side addressing ----
  const int arow0 = bhalf * 96 + wm * 48 + 0 * 16 + (lane & 15);
  const int arow1 = arow0 + 16;
  const int arow2 = arow0 + 32;
  const int koff  = wk * 256 + (lane >> 4) * 8;                    // u16 units
  const u16* wb   = wpack + (size_t)(dir * 64 + jsl) * 65536
                          + (size_t)wk * 8 * 2048 + lane * 8;      // cached (L2) W stream

  // partial-logits base for this block's contention group (dir, jsl&7)
  float* pbase = part + ((size_t)(dir * 8 + (jsl & 7)) * BATCH) * T_STEPS;

  // barrier pointers (monotonic, 64B-spaced)
  unsigned* g1  = bar + (grp << 8) + ((jsl >> 3) << 4);
  unsigned* g2  = bar + (grp << 8) + 128;
  unsigned* rel = bar + (grp << 8) + 144;

  // dump base: row = wm*48 + (lane>>4)*4 (+ mt*16 + r), col = lane&15 (+ n*16)
  float* dbase = DMP + (size_t)wk * DMP_WK_STRIDE
                     + (wm * 48 + (lane >> 4) * 4) * 68 + (lane & 15);
  const int goff = rgrp * 3 * 68 + jj * 4;      // gather base (row rgrp*3, col jj*4)

  float lpv[3];
  int   lpo[3];

  __syncthreads();

  for (int s = 0; s < T_STEPS; ++s) {
    const int rbuf = s & 1;
    const u16* hsrc = hb + ((size_t)(dir * 2 + rbuf)) * BATCH * HID;
    u16*       hdst = hb + ((size_t)(dir * 2 + (rbuf ^ 1))) * BATCH * HID;
    const u16* ab0 = hsrc + (size_t)arow0 * HID + koff;
    const u16* ab1 = hsrc + (size_t)arow1 * HID + koff;
    const u16* ab2 = hsrc + (size_t)arow2 * HID + koff;

    f32x4 acc[3][4];
    #pragma unroll
    for (int mt = 0; mt < 3; ++mt)
      #pragma unroll
      for (int n = 0; n < 4; ++n)
        acc[mt][n] = (f32x4){0.f, 0.f, 0.f, 0.f};

    u32x4 aq[4][3];
    u32x4 bq[4][4];

    // 8 K-chunks of 32; depth-3 ring-4 prefetch for A and B, counted vmcnt
    ALD(0, 0)   BLD(0, 0) SB
    ALD(1, 64)  BLD(1, 1) SB
    ALD(2, 128) BLD(2, 2) SB

    ALD(3, 192) BLD(3, 3) WB(21) MM(0)
    ALD(0, 256) BLD(0, 4) WB(21) MM(1)
    ALD(1, 320) BLD(1, 5) WB(21) MM(2)
    ALD(2, 384) BLD(2, 6) WB(21) MM(3)
    ALD(3, 448) BLD(3, 7) WB(21) MM(4)
                          WB(14) MM(5)
                          WB(7)  MM(6)
                          WB(0)  MM(7)

    // ---- dump raw partials, conflict-free: [wk][row][col(+4 pad)] ----
    #pragma unroll
    for (int mt = 0; mt < 3; ++mt)
      #pragma unroll
      for (int n = 0; n < 4; ++n)
        #pragma unroll
        for (int r = 0; r < 4; ++r)
          dbase[(mt * 16 + r) * 68 + n * 16] = acc[mt][n][r];
    __syncthreads();

    const int t_x = dir ? (T_STEPS - 1 - s) : s;

    // ---- gather wk-sum (4x ds_read_b128) + pointwise ----
    #pragma unroll
    for (int mt = 0; mt < 3; ++mt) {
      const int ga = goff + mt * 68;
      f32x4 p0 = *(const f32x4*)(DMP + 0 * DMP_WK_STRIDE + ga);
      f32x4 p1 = *(const f32x4*)(DMP + 1 * DMP_WK_STRIDE + ga);
      f32x4 p2 = *(const f32x4*)(DMP + 2 * DMP_WK_STRIDE + ga);
      f32x4 p3 = *(const f32x4*)(DMP + 3 * DMP_WK_STRIDE + ga);
      f32x4 g4 = (p0 + p1) + (p2 + p3);          // components = gates (i,f,g,o)
      int bg = bgm[mt];
      float2 xv = *(const float2*)(x + ((size_t)t_x * BATCH + bg) * 2);
      float pi = g4[0] + cf0.x * xv.x + cf0.y * xv.y + cf0.z;
      float pf = g4[1] + cf1.x * xv.x + cf1.y * xv.y + cf1.z;
      float pg = g4[2] + cf2.x * xv.x + cf2.y * xv.y + cf2.z;
      float po = g4[3] + cf3.x * xv.x + cf3.y * xv.y + cf3.z;
      float ig = sigm(pi), fg = sigm(pf), gv = tanh_f(pg), og = sigm(po);
      float c = fg * creg[mt] + ig * gv;
      creg[mt] = c;
      float h = og * tanh_f(c);
      u16* hp = hdst + (size_t)bg * HID + jglob;
      unsigned hv = (unsigned)f2bf(h);
      HST(hp, hv);
      float lp = h * wlg;
      lp += __shfl_xor(lp, 1);
      lp += __shfl_xor(lp, 2);
      lp += __shfl_xor(lp, 4);
      lp += __shfl_xor(lp, 8);
      lpv[mt] = lp;
      lpo[mt] = bg * T_STEPS + t_x;
    }

    // ---- drain h stores to coherence point, then block-wide sync ----
    asm volatile("s_waitcnt vmcnt(0)" ::: "memory");
    __syncthreads();

    // ---- partial-logit atomics (8 contenders, same-XCD), off the drain path ----
    if (jj == 0) {
      atomicAdd(&pbase[lpo[0]], lpv[0]);
      atomicAdd(&pbase[lpo[1]], lpv[1]);
      atomicAdd(&pbase[lpo[2]], lpv[2]);
    }

    // ---- two-level tree barrier over the 64-block (dir,bhalf) group ----
    if (tid == 0) {
      bool last = false;
      unsigned o1 = __hip_atomic_fetch_add(g1, 1u, __ATOMIC_RELAXED, __HIP_MEMORY_SCOPE_AGENT);
      if (o1 == (unsigned)(s * 8 + 7)) {
        unsigned o2 = __hip_atomic_fetch_add(g2, 1u, __ATOMIC_RELAXED, __HIP_MEMORY_SCOPE_AGENT);
        if (o2 == (unsigned)(s * 8 + 7)) {
          unsigned rv = (unsigned)(s + 1);
          asm volatile("global_store_dword %0, %1, off sc0 sc1" :: "v"(rel), "v"(rv) : "memory");
          last = true;
        }
      }
      if (!last) {
        long guard = 0;
        unsigned rv;
        for (;;) {
          asm volatile("global_load_dword %0, %1, off sc0 sc1" : "=v"(rv) : "v"(rel));
          asm volatile("s_waitcnt vmcnt(0)" ::: "memory");
          if ((int)rv >= s + 1) break;
          if (++guard > (1L << 20)) { *ldsflag = 1; break; }
          __builtin_amdgcn_s_sleep(2);
        }
      }
    }
    __syncthreads();
    if (*ldsflag) return;   // sync failure: bail instead of hanging
  }
}

// ---------------- post: sum partials -> softmax -> cumsum -> Bezier -> curves + reg ----------------
__global__ void post_k(const float* __restrict__ part, const float* __restrict__ ctrl,
                       const float* __restrict__ ratw, float* __restrict__ out)
{
  __shared__ float sh[T_STEPS + 64];
  const int b = blockIdx.x;
  const int t = threadIdx.x;          // 320 threads
  float l = 0.f;
  #pragma unroll
  for (int p = 0; p < 16; ++p)
    l += part[((size_t)p * BATCH + b) * T_STEPS + t];
  sh[t] = l;
  __syncthreads();
  if (t < 64) {
    float mm = sh[t];
    for (int i = t + 64; i < T_STEPS; i += 64) mm = fmaxf(mm, sh[i]);
    #pragma unroll
    for (int o = 32; o; o >>= 1) mm = fmaxf(mm, __shfl_xor(mm, o));
    if (t == 0) sh[T_STEPS] = mm;
  }
  __syncthreads();
  const float m = sh[T_STEPS];
  float e = __expf(l - m);
  __syncthreads();
  sh[t] = e;
  __syncthreads();
  for (int off = 1; off < T_STEPS; off <<= 1) {
    float v = (t >= off) ? sh[t - off] : 0.f;
    __syncthreads();
    sh[t] += v;
    __syncthreads();
  }
  const float total = sh[T_STEPS - 1];
  const float ts = sh[t] / total;

  float px[8], py[8], rr[8];
  #pragma unroll
  for (int n = 0; n < 8; ++n) {
    px[n] = ctrl[b * 16 + 2 * n];
    py[n] = ctrl[b * 16 + 2 * n + 1];
    rr[n] = ratw[b * 8 + n];
  }
  const float C[8] = {1.f, 7.f, 21.f, 35.f, 35.f, 21.f, 7.f, 1.f};
  float tp[8], up[8];
  tp[0] = 1.f; up[0] = 1.f;
  const float u = 1.f - ts;
  #pragma unroll
  for (int n = 1; n < 8; ++n) { tp[n] = tp[n - 1] * ts; up[n] = up[n - 1] * u; }
  float den = 0.f, nx = 0.f, ny = 0.f;
  #pragma unroll
  for (int n = 0; n < 8; ++n) {
    float w = C[n] * tp[n] * up[7 - n] * rr[n];
    den += w; nx += w * px[n]; ny += w * py[n];
  }
  out[(b * T_STEPS + t) * 2 + 0] = nx / den;
  out[(b * T_STEPS + t) * 2 + 1] = ny / den;

  if (b == 0) {   // regularizer scalar
    __syncthreads();
    if (t < BATCH) {
      float s2 = 0.f;
      #pragma unroll
      for (int n = 0; n < 7; ++n) {
        float dx = ctrl[t * 16 + 2 * n + 2] - ctrl[t * 16 + 2 * n + 0];
        float dy = ctrl[t * 16 + 2 * n + 3] - ctrl[t * 16 + 2 * n + 1];
        s2 += dx * dx + dy * dy;
      }
      sh[t] = s2;
    }
    __syncthreads();
    if (t == 0) {
      float tot = 0.f;
      for (int i = 0; i < BATCH; ++i) tot += sh[i];
      out[BATCH * T_STEPS * 2] = tot / (float)(BATCH * 7);
    }
  }
}

extern "C" void kernel_launch(void* const* d_in, const int* in_sizes, int n_in,
                              void* d_out, int out_size, void* d_ws, size_t ws_size,
                              hipStream_t stream)
{
  const float* x    = (const float*)d_in[0];
  const float* ctrl = (const float*)d_in[1];
  const float* ratw = (const float*)d_in[2];
  const float* Whf  = (const float*)d_in[3];
  const float* bhf  = (const float*)d_in[4];
  const float* Whb  = (const float*)d_in[5];
  const float* bhb  = (const float*)d_in[6];
  const float* Wcf  = (const float*)d_in[7];
  const float* bcf  = (const float*)d_in[8];
  const float* Wcb  = (const float*)d_in[9];
  const float* bcb  = (const float*)d_in[10];
  const float* Wihf = (const float*)d_in[11];
  const float* Whhf = (const float*)d_in[12];
  const float* bihf = (const float*)d_in[13];
  const float* bhhf = (const float*)d_in[14];
  const float* Wihb = (const float*)d_in[15];
  const float* Whhb = (const float*)d_in[16];
  const float* bihb = (const float*)d_in[17];
  const float* bhhb = (const float*)d_in[18];
  const float* Wlog = (const float*)d_in[19];
  float* out = (float*)d_out;
  char*  ws  = (char*)d_ws;
  if (ws_size < (size_t)WS_NEED) return;

  unsigned* bar    = (unsigned*)(ws + OFF_BAR);
  float*    part   = (float*)(ws + OFF_PART);
  float*    c0     = (float*)(ws + OFF_C0);
  u16*      hb     = (u16*)(ws + OFF_H);
  u16*      wpack  = (u16*)(ws + OFF_WPACK);
  float*    coef   = (float*)(ws + OFF_COEF);

  hipMemsetAsync(ws, 0, MEMSET_BYTES, stream);   // bar + partial logits
  pack_k<<<4096, 256, 0, stream>>>(Whhf, Whhb, wpack);
  coef_k<<<32, 256, 0, stream>>>(Wihf, bihf, bhhf, Wihb, bihb, bhhb, coef);
  init_k<<<dim3(768, 4), 256, 0, stream>>>(ctrl, ratw, Whf, bhf, Whb, bhb,
                                           Wcf, bcf, Wcb, bcb, hb, c0);
  hipFuncSetAttribute((const void*)lstm_persist,
                      hipFuncAttributeMaxDynamicSharedMemorySize, DYN_LDS);
  lstm_persist<<<NBLK, 512, DYN_LDS, stream>>>(x, Wlog, part, c0, hb, wpack, coef, bar);
  post_k<<<BATCH, T_STEPS, 0, stream>>>(part, ctrl, ratw, out);
}